// Round 14
// baseline (148.284 us; speedup 1.0000x reference)
//
#include <hip/hip_runtime.h>
#include <math.h>

#define B_SIZE 8192
#define D_SIZE 256
#define N_CLS 1024
#define CLS_CAP 64
#define PCAP 256
#define ALPHA 2.0f
#define BETA 50.0f
#define BASE 0.5f
#define MARGIN 0.1f

// neg GEMM: exact r9/r12 config (43.6 us proven): 128x128 single tile/block,
// BK=32 double-buffered LDS, 4 waves, (256,3), sentinel epilogue + per-fj
// fences, part[k*B+row] line-exclusive writes (no false sharing).
// r13/r14: rowred_kernel reduces over k during a coalesced column pass
// (register accumulation, no LDS, no transposed copy) -> final_kernel reads
// one precomputed scalar pair per row. r14 = byte-identical A/B resubmission
// of r13 (its +22us total had no kernel-level cause; suspect run variance).
#define TM 128
#define TK 32
#define NT (B_SIZE / TM)            // 64 tiles per dim
#define NBLK (NT * (NT + 1) / 2)    // 2080 triangular tiles
#define NCONV (B_SIZE * D_SIZE / 1024)   // 2048 convert blocks

typedef __attribute__((ext_vector_type(8))) __bf16 bf16x8;
typedef __attribute__((ext_vector_type(4))) float f32x4;

__device__ __forceinline__ unsigned int enc_f32(float f) {
    unsigned int u = __float_as_uint(f);
    return (u & 0x80000000u) ? ~u : (u | 0x80000000u);
}
__device__ __forceinline__ float dec_f32(unsigned int e) {
    unsigned int u = (e & 0x80000000u) ? (e ^ 0x80000000u) : ~e;
    return __uint_as_float(u);
}

__device__ __forceinline__ unsigned short f2bf(float x) {
    unsigned int u = __float_as_uint(x);
    u += 0x7FFFu + ((u >> 16) & 1u);   // RNE
    return (unsigned short)(u >> 16);
}

__device__ __forceinline__ void glds16(const unsigned short* g, const unsigned char* l) {
    __builtin_amdgcn_global_load_lds((const __attribute__((address_space(1))) void*)g,
                                     (__attribute__((address_space(3))) void*)l, 16, 0, 0);
}

// fast 2^x: v_exp_f32 directly (HIP has no __exp2f; glibc macro collision)
__device__ __forceinline__ float fexp2(float x) {
    return __builtin_amdgcn_exp2f(x);
}

// DPP lane-XOR within 16 lanes (VALU pipe, low latency); bit-identical to
// the __shfl_xor butterfly (group totals lane-replicated at each step).
template <int C>
__device__ __forceinline__ float dppx(float x) {
    return __builtin_bit_cast(float, __builtin_amdgcn_update_dpp(
        0, __builtin_bit_cast(int, x), C, 0xF, 0xF, true));
}
__device__ __forceinline__ void red16(float& s, float& m) {
    s += dppx<0xB1>(s);  m = fmaxf(m, dppx<0xB1>(m));
    s += dppx<0x4E>(s);  m = fmaxf(m, dppx<0x4E>(m));
    s += dppx<0x141>(s); m = fmaxf(m, dppx<0x141>(m));
    s += dppx<0x140>(s); m = fmaxf(m, dppx<0x140>(m));
}

// decode unordered pair index p -> (a, b), 0 <= b < a
__device__ __forceinline__ void pair_decode(int p, int& a, int& b) {
    a = (int)((1.0f + sqrtf(1.0f + 8.0f * (float)p)) * 0.5f);
    while (a * (a - 1) / 2 > p) --a;
    while ((a + 1) * a / 2 <= p) ++a;
    b = p - a * (a - 1) / 2;
}

// ---- K1: fused class-blocks (0..N_CLS) + convert blocks (N_CLS..) ----
__global__ __launch_bounds__(256) void conv_pos_kernel(
    const float* __restrict__ emb, const int* __restrict__ labels,
    unsigned short* __restrict__ embb,
    float* __restrict__ pos_min, float* __restrict__ psims,
    int* __restrict__ cls_cnt, int* __restrict__ cls_rows) {
    int t = threadIdx.x;
    if (blockIdx.x >= N_CLS) {
        int i = ((blockIdx.x - N_CLS) * 256 + t) * 4;
        float4 v = *(const float4*)(&emb[i]);
        ushort4 o;
        o.x = f2bf(v.x); o.y = f2bf(v.y); o.z = f2bf(v.z); o.w = f2bf(v.w);
        *(ushort4*)(&embb[i]) = o;
        return;
    }
    int cls = blockIdx.x;
    __shared__ int rs[CLS_CAP];
    __shared__ unsigned int smin[CLS_CAP];
    __shared__ int lcnt;
    if (t == 0) lcnt = 0;
    if (t < CLS_CAP) smin[t] = 0xFF800000u;  // enc(+inf)
    __syncthreads();
    const int4* lab4 = (const int4*)labels;
    for (int i = t; i < B_SIZE / 4; i += 256) {
        int4 L = lab4[i];
        if (L.x == cls) { int p = atomicAdd(&lcnt, 1); if (p < CLS_CAP) rs[p] = 4 * i; }
        if (L.y == cls) { int p = atomicAdd(&lcnt, 1); if (p < CLS_CAP) rs[p] = 4 * i + 1; }
        if (L.z == cls) { int p = atomicAdd(&lcnt, 1); if (p < CLS_CAP) rs[p] = 4 * i + 2; }
        if (L.w == cls) { int p = atomicAdd(&lcnt, 1); if (p < CLS_CAP) rs[p] = 4 * i + 3; }
    }
    __syncthreads();
    int c = min(lcnt, CLS_CAP);
    if (t == 0) cls_cnt[cls] = c;
    if (t < c) cls_rows[cls * CLS_CAP + t] = rs[t];
    int np = c * (c - 1) / 2;
    for (int base = 0; base < np * 8; base += 256) {
        int slot = base + t;
        if (slot < np * 8) {
            int p = slot >> 3, l = slot & 7;   // 8 aligned lanes per pair
            int a, b; pair_decode(p, a, b);
            const float4* pa = (const float4*)(emb + (size_t)rs[a] * D_SIZE) + l * 8;
            const float4* pb = (const float4*)(emb + (size_t)rs[b] * D_SIZE) + l * 8;
            float s = 0.0f;
#pragma unroll
            for (int k = 0; k < 8; ++k) {
                float4 x = pa[k], y = pb[k];
                s = fmaf(x.x, y.x, fmaf(x.y, y.y, fmaf(x.z, y.z, fmaf(x.w, y.w, s))));
            }
            s += __shfl_xor(s, 1, 64);
            s += __shfl_xor(s, 2, 64);
            s += __shfl_xor(s, 4, 64);
            if (l == 0) {
                if (p < PCAP) psims[cls * PCAP + p] = s;
                unsigned int e = enc_f32(s);
                atomicMin(&smin[a], e);
                atomicMin(&smin[b], e);
            }
        }
    }
    __syncthreads();
    if (t < c) pos_min[rs[t]] = dec_f32(smin[t]);
}

// ---- K2: the ONE GEMM (triangular tiles) — exact r9/r12 body ----
// part[k*B + row]: m-side writes k=bj (bj>=bi), n-side k=bi (bi<bj);
// every line written by exactly one tile (no false sharing).
// C/D layout (16x16x32): col = lane&15, row = (lane>>4)*4 + reg  [m89/m91]
__global__ __launch_bounds__(256, 3) void neg_kernel(
    const unsigned short* __restrict__ embb, const int* __restrict__ labels,
    const float* __restrict__ pos_min,
    float* __restrict__ part_sum, float* __restrict__ part_max)
{
    // XCD-aware bijective swizzle (2080 % 8 == 0), then triangular decode
    int bt = (blockIdx.x & 7) * (NBLK >> 3) + (blockIdx.x >> 3);
    int bi = 0, rem = bt;
    while (rem >= (NT - bi)) { rem -= (NT - bi); ++bi; }
    const int bj = bi + rem;
    const int m0 = bi * TM, n0 = bj * TM;
    const bool isdiag = (bi == bj);

    const int tid = threadIdx.x;
    const int lane = tid & 63;
    const int w = tid >> 6;
    const int wm = w >> 1, wn = w & 1;

    __shared__ unsigned char As[2][TM * 64];
    __shared__ unsigned char Bs[2][TM * 64];

    const unsigned short* gA[2];
    const unsigned short* gB[2];
    int lofs[2];
#pragma unroll
    for (int s = 0; s < 2; ++s) {
        int r = w * 32 + s * 16 + (lane >> 2);
        int c = (lane & 3) ^ ((r >> 1) & 3);
        gA[s] = embb + (size_t)(m0 + r) * D_SIZE + c * 8;
        gB[s] = embb + (size_t)(n0 + r) * D_SIZE + c * 8;
        lofs[s] = (w * 32 + s * 16) * 64;
    }
#pragma unroll
    for (int s = 0; s < 2; ++s) { glds16(gA[s], As[0] + lofs[s]); glds16(gB[s], Bs[0] + lofs[s]); }

    const int col = lane & 15;
    const int quad = lane >> 4;
    const int xsw = (quad ^ ((col >> 1) & 3)) * 16;
    const int aoff0 = (wm * 64 + col) * 64 + xsw;
    const int boff0 = (wn * 64 + col) * 64 + xsw;

    f32x4 acc[4][4];
#pragma unroll
    for (int fi = 0; fi < 4; ++fi)
#pragma unroll
        for (int fj = 0; fj < 4; ++fj)
            acc[fi][fj] = (f32x4){0.0f, 0.0f, 0.0f, 0.0f};

#pragma unroll
    for (int it = 0; it < D_SIZE / TK; ++it) {
        const int st = it & 1;
        __syncthreads();   // stage st's staging complete
        if (it + 1 < D_SIZE / TK) {
            const int k1 = (it + 1) * TK;
#pragma unroll
            for (int s = 0; s < 2; ++s) {
                glds16(gA[s] + k1, As[st ^ 1] + lofs[s]);
                glds16(gB[s] + k1, Bs[st ^ 1] + lofs[s]);
            }
        }
        bf16x8 af[4], bf[4];
#pragma unroll
        for (int f = 0; f < 4; ++f) {
            af[f] = __builtin_bit_cast(bf16x8, *(const uint4*)(As[st] + aoff0 + f * 1024));
            bf[f] = __builtin_bit_cast(bf16x8, *(const uint4*)(Bs[st] + boff0 + f * 1024));
        }
#pragma unroll
        for (int fi = 0; fi < 4; ++fi)
#pragma unroll
            for (int fj = 0; fj < 4; ++fj)
                acc[fi][fj] = __builtin_amdgcn_mfma_f32_16x16x32_bf16(
                    af[fi], bf[fj], acc[fi][fj], 0, 0, 0);
    }

    // ---- branch-free sentinel epilogue, sched-fenced per fj-group ----
    const float K1 = 72.13475204444817f;   /* BETA*log2(e) */
    const float K2 = -36.067376022224085f; /* -BETA*BASE*log2(e) */
    int ljv[4]; float pmc[4], nsn[4], nmx[4];
#pragma unroll
    for (int fj = 0; fj < 4; ++fj) {
        int cl = wn * 64 + fj * 16 + col;
        ljv[fj] = labels[n0 + cl];
        pmc[fj] = pos_min[n0 + cl] - MARGIN;
        nsn[fj] = 0.0f;
        nmx[fj] = -3.0f;
    }

#pragma unroll
    for (int fi = 0; fi < 4; ++fi) {
        int gi0 = m0 + wm * 64 + fi * 16 + quad * 4;
        int lir[4]; float pmr[4], msn[4], mmx[4];
#pragma unroll
        for (int r = 0; r < 4; ++r) {
            lir[r] = labels[gi0 + r];
            pmr[r] = pos_min[gi0 + r] - MARGIN;
            msn[r] = 0.0f;
            mmx[r] = -3.0f;
        }
        __builtin_amdgcn_sched_barrier(0);
#pragma unroll
        for (int fj = 0; fj < 4; ++fj) {
#pragma unroll
            for (int r = 0; r < 4; ++r) {
                float s = acc[fi][fj][r];
                float sm = (lir[r] != ljv[fj]) ? s : -3.0f;
                float e = fexp2(fmaf(sm, K1, K2));
                mmx[r] = fmaxf(mmx[r], sm);
                nmx[fj] = fmaxf(nmx[fj], sm);
                msn[r] += (sm > pmr[r]) ? e : 0.0f;
                nsn[fj] += (sm > pmc[fj]) ? e : 0.0f;
            }
            __builtin_amdgcn_sched_barrier(0);
        }
        // 16-lane (col) reduction via DPP — VALU, no LDS pipe
#pragma unroll
        for (int r = 0; r < 4; ++r) red16(msn[r], mmx[r]);
        if (col == 0) {
            *(float4*)(&part_sum[(size_t)bj * B_SIZE + gi0]) =
                make_float4(msn[0], msn[1], msn[2], msn[3]);
            *(float4*)(&part_max[(size_t)bj * B_SIZE + gi0]) =
                make_float4(mmx[0], mmx[1], mmx[2], mmx[3]);
        }
        __builtin_amdgcn_sched_barrier(0);
    }
    if (!isdiag) {
#pragma unroll
        for (int m = 16; m < 64; m <<= 1) {
#pragma unroll
            for (int fj = 0; fj < 4; ++fj) {
                nsn[fj] += __shfl_xor(nsn[fj], m, 64);
                nmx[fj] = fmaxf(nmx[fj], __shfl_xor(nmx[fj], m, 64));
            }
        }
        if (quad == 0) {
#pragma unroll
            for (int fj = 0; fj < 4; ++fj) {
                int gj = n0 + wn * 64 + fj * 16 + col;
                part_sum[(size_t)bi * B_SIZE + gj] = nsn[fj];
                part_max[(size_t)bi * B_SIZE + gj] = nmx[fj];
            }
        }
    }
}

// ---- K2b: per-row reduction over the 64 k-slots (coalesced, in-register) ----
// Thread t of block b owns row r = b*256+t; loop over k reads
// part[k*B + r] -- consecutive lanes hit consecutive addresses. Sums in
// ascending-k order (bit-identical to the verified reduction).
__global__ __launch_bounds__(256) void rowred_kernel(
    const float* __restrict__ part_sum, const float* __restrict__ part_max,
    float* __restrict__ row_sum, float* __restrict__ row_max) {
    const int r = blockIdx.x * 256 + threadIdx.x;
    float s = 0.0f, m = -__builtin_inff();
#pragma unroll
    for (int k = 0; k < NT; ++k) {
        s += part_sum[(size_t)k * B_SIZE + r];
        m = fmaxf(m, part_max[(size_t)k * B_SIZE + r]);
    }
    row_sum[r] = s;
    row_max[r] = m;
}

// ---- K3: per-class term from precomputed row_sum/row_max + psims ----
__global__ __launch_bounds__(256) void final_kernel(
    const float* __restrict__ emb, const int* __restrict__ cls_cnt,
    const int* __restrict__ cls_rows, const float* __restrict__ psims,
    const float* __restrict__ row_sum, const float* __restrict__ row_max,
    float* __restrict__ cls_term, float* __restrict__ cls_valid) {
    int cls = blockIdx.x;
    __shared__ int rs[CLS_CAP];
    __shared__ float snm[CLS_CAP];
    __shared__ float sneg[CLS_CAP];
    __shared__ float ssum[CLS_CAP];
    int t = threadIdx.x;
    int c = min(cls_cnt[cls], CLS_CAP);
    if (t < CLS_CAP) ssum[t] = 0.0f;
    if (t < c) rs[t] = cls_rows[cls * CLS_CAP + t];
    __syncthreads();
    if (t < c) {
        int row = rs[t];
        sneg[t] = row_sum[row];
        snm[t] = row_max[row];
    }
    __syncthreads();
    int np = c * (c - 1) / 2;
    if (np <= PCAP) {
        for (int p = t; p < np; p += 256) {
            float s = psims[cls * PCAP + p];
            int a, b; pair_decode(p, a, b);
            float e = __expf(-ALPHA * (s - BASE));
            if (s - MARGIN < snm[a]) atomicAdd(&ssum[a], e);
            if (s - MARGIN < snm[b]) atomicAdd(&ssum[b], e);
        }
    } else {
        // fallback: recompute dots, 8 lanes per pair
        for (int base = 0; base < np * 8; base += 256) {
            int slot = base + t;
            if (slot < np * 8) {
                int p = slot >> 3, l = slot & 7;
                int a, b; pair_decode(p, a, b);
                const float4* pa = (const float4*)(emb + (size_t)rs[a] * D_SIZE) + l * 8;
                const float4* pb = (const float4*)(emb + (size_t)rs[b] * D_SIZE) + l * 8;
                float s = 0.0f;
#pragma unroll
                for (int k = 0; k < 8; ++k) {
                    float4 x = pa[k], y = pb[k];
                    s = fmaf(x.x, y.x, fmaf(x.y, y.y, fmaf(x.z, y.z, fmaf(x.w, y.w, s))));
                }
                s += __shfl_xor(s, 1, 64);
                s += __shfl_xor(s, 2, 64);
                s += __shfl_xor(s, 4, 64);
                if (l == 0) {
                    float e = __expf(-ALPHA * (s - BASE));
                    if (s - MARGIN < snm[a]) atomicAdd(&ssum[a], e);
                    if (s - MARGIN < snm[b]) atomicAdd(&ssum[b], e);
                }
            }
        }
    }
    __syncthreads();
    // per-class term: rows live on threads 0..c-1 (all in wave 0) -> shfl reduce
    if (t < 64) {
        float term = 0.0f, valid = 0.0f;
        if (t < c) {
            float sp = ssum[t], sn = sneg[t];
            if (sp > 0.0f && sn > 0.0f) {
                term = log1pf(sp) * (1.0f / ALPHA) + log1pf(sn) * (1.0f / BETA);
                valid = 1.0f;
            }
        }
#pragma unroll
        for (int m = 1; m < 64; m <<= 1) {
            term += __shfl_xor(term, m, 64);
            valid += __shfl_xor(valid, m, 64);
        }
        if (t == 0) { cls_term[cls] = term; cls_valid[cls] = valid; }
    }
}

// ---- K4: fold 1024 class terms -> out ----
__global__ __launch_bounds__(256) void finalize_kernel(
    const float* __restrict__ cls_term, const float* __restrict__ cls_valid,
    float* __restrict__ out) {
    __shared__ float st[256];
    __shared__ float sc[256];
    int t = threadIdx.x;
    float tot = 0.0f, cnt = 0.0f;
#pragma unroll
    for (int i = 0; i < N_CLS / 256; ++i) {
        tot += cls_term[i * 256 + t];
        cnt += cls_valid[i * 256 + t];
    }
    st[t] = tot; sc[t] = cnt;
    __syncthreads();
    for (int s = 128; s > 0; s >>= 1) {
        if (t < s) { st[t] += st[t + s]; sc[t] += sc[t + s]; }
        __syncthreads();
    }
    if (t == 0) out[0] = st[0] / fmaxf(sc[0], 1.0f);
}

extern "C" void kernel_launch(void* const* d_in, const int* in_sizes, int n_in,
                              void* d_out, int out_size, void* d_ws, size_t ws_size,
                              hipStream_t stream) {
    const float* emb = (const float*)d_in[0];
    const int* labels = (const int*)d_in[1];
    float* out = (float*)d_out;

    // ws: embb 4MB | part_sum 2MB | part_max 2MB | row_sum 32KB | row_max 32KB |
    //     psims 1MB | cls_rows 256KB | pos_min 32KB | cls_term/valid/cnt
    unsigned short* embb = (unsigned short*)d_ws;
    float* part_sum = (float*)(embb + (size_t)B_SIZE * D_SIZE);
    float* part_max = part_sum + (size_t)NT * B_SIZE;
    float* row_sum = part_max + (size_t)NT * B_SIZE;
    float* row_max = row_sum + B_SIZE;
    float* psims = row_max + B_SIZE;
    int* cls_rows = (int*)(psims + (size_t)N_CLS * PCAP);
    float* pos_min = (float*)(cls_rows + N_CLS * CLS_CAP);
    float* cls_term = pos_min + B_SIZE;
    float* cls_valid = cls_term + N_CLS;
    int* cls_cnt = (int*)(cls_valid + N_CLS);

    conv_pos_kernel<<<dim3(N_CLS + NCONV), dim3(256), 0, stream>>>(
        emb, labels, embb, pos_min, psims, cls_cnt, cls_rows);
    neg_kernel<<<dim3(NBLK), dim3(256), 0, stream>>>(
        embb, labels, pos_min, part_sum, part_max);
    rowred_kernel<<<dim3(B_SIZE / 256), dim3(256), 0, stream>>>(
        part_sum, part_max, row_sum, row_max);
    final_kernel<<<dim3(N_CLS), dim3(256), 0, stream>>>(
        emb, cls_cnt, cls_rows, psims, row_sum, row_max, cls_term, cls_valid);
    finalize_kernel<<<dim3(1), dim3(256), 0, stream>>>(cls_term, cls_valid, out);
}

// Round 15
// 125.205 us; speedup vs baseline: 1.1843x; 1.1843x over previous
//
#include <hip/hip_runtime.h>
#include <math.h>

#define B_SIZE 8192
#define D_SIZE 256
#define N_CLS 1024
#define CLS_CAP 64
#define PCAP 256
#define ALPHA 2.0f
#define BETA 50.0f
#define BASE 0.5f
#define MARGIN 0.1f

// neg GEMM: exact r9 config (43.6 us proven): 128x128 single tile/block,
// BK=32 double-buffered LDS, 4 waves, (256,3), sentinel epilogue + per-fj
// fences, part[k*B+row] line-exclusive writes (no false sharing).
// transpose kernel part[k*B+row] -> partT[row*64+k] so final_kernel
// reads coalesced float4 (r10: scattered-read final costs ~20-30us;
// r11: transposed-direct-from-neg causes cross-XCD false sharing;
// r13/r14 A/B: rowred fusion loses 22us -- 32-block latency-bound pass).
#define TM 128
#define TK 32
#define NT (B_SIZE / TM)            // 64 tiles per dim
#define NBLK (NT * (NT + 1) / 2)    // 2080 triangular tiles
#define NCONV (B_SIZE * D_SIZE / 1024)   // 2048 convert blocks

typedef __attribute__((ext_vector_type(8))) __bf16 bf16x8;
typedef __attribute__((ext_vector_type(4))) float f32x4;

__device__ __forceinline__ unsigned int enc_f32(float f) {
    unsigned int u = __float_as_uint(f);
    return (u & 0x80000000u) ? ~u : (u | 0x80000000u);
}
__device__ __forceinline__ float dec_f32(unsigned int e) {
    unsigned int u = (e & 0x80000000u) ? (e ^ 0x80000000u) : ~e;
    return __uint_as_float(u);
}

__device__ __forceinline__ unsigned short f2bf(float x) {
    unsigned int u = __float_as_uint(x);
    u += 0x7FFFu + ((u >> 16) & 1u);   // RNE
    return (unsigned short)(u >> 16);
}

__device__ __forceinline__ void glds16(const unsigned short* g, const unsigned char* l) {
    __builtin_amdgcn_global_load_lds((const __attribute__((address_space(1))) void*)g,
                                     (__attribute__((address_space(3))) void*)l, 16, 0, 0);
}

// fast 2^x: v_exp_f32 directly (HIP has no __exp2f; glibc macro collision)
__device__ __forceinline__ float fexp2(float x) {
    return __builtin_amdgcn_exp2f(x);
}

// DPP lane-XOR within 16 lanes (VALU pipe, low latency); bit-identical to
// the __shfl_xor butterfly (group totals lane-replicated at each step).
template <int C>
__device__ __forceinline__ float dppx(float x) {
    return __builtin_bit_cast(float, __builtin_amdgcn_update_dpp(
        0, __builtin_bit_cast(int, x), C, 0xF, 0xF, true));
}
__device__ __forceinline__ void red16(float& s, float& m) {
    s += dppx<0xB1>(s);  m = fmaxf(m, dppx<0xB1>(m));
    s += dppx<0x4E>(s);  m = fmaxf(m, dppx<0x4E>(m));
    s += dppx<0x141>(s); m = fmaxf(m, dppx<0x141>(m));
    s += dppx<0x140>(s); m = fmaxf(m, dppx<0x140>(m));
}

// decode unordered pair index p -> (a, b), 0 <= b < a
__device__ __forceinline__ void pair_decode(int p, int& a, int& b) {
    a = (int)((1.0f + sqrtf(1.0f + 8.0f * (float)p)) * 0.5f);
    while (a * (a - 1) / 2 > p) --a;
    while ((a + 1) * a / 2 <= p) ++a;
    b = p - a * (a - 1) / 2;
}

// ---- K1: fused class-blocks (0..N_CLS) + convert blocks (N_CLS..) ----
__global__ __launch_bounds__(256) void conv_pos_kernel(
    const float* __restrict__ emb, const int* __restrict__ labels,
    unsigned short* __restrict__ embb,
    float* __restrict__ pos_min, float* __restrict__ psims,
    int* __restrict__ cls_cnt, int* __restrict__ cls_rows) {
    int t = threadIdx.x;
    if (blockIdx.x >= N_CLS) {
        int i = ((blockIdx.x - N_CLS) * 256 + t) * 4;
        float4 v = *(const float4*)(&emb[i]);
        ushort4 o;
        o.x = f2bf(v.x); o.y = f2bf(v.y); o.z = f2bf(v.z); o.w = f2bf(v.w);
        *(ushort4*)(&embb[i]) = o;
        return;
    }
    int cls = blockIdx.x;
    __shared__ int rs[CLS_CAP];
    __shared__ unsigned int smin[CLS_CAP];
    __shared__ int lcnt;
    if (t == 0) lcnt = 0;
    if (t < CLS_CAP) smin[t] = 0xFF800000u;  // enc(+inf)
    __syncthreads();
    const int4* lab4 = (const int4*)labels;
    for (int i = t; i < B_SIZE / 4; i += 256) {
        int4 L = lab4[i];
        if (L.x == cls) { int p = atomicAdd(&lcnt, 1); if (p < CLS_CAP) rs[p] = 4 * i; }
        if (L.y == cls) { int p = atomicAdd(&lcnt, 1); if (p < CLS_CAP) rs[p] = 4 * i + 1; }
        if (L.z == cls) { int p = atomicAdd(&lcnt, 1); if (p < CLS_CAP) rs[p] = 4 * i + 2; }
        if (L.w == cls) { int p = atomicAdd(&lcnt, 1); if (p < CLS_CAP) rs[p] = 4 * i + 3; }
    }
    __syncthreads();
    int c = min(lcnt, CLS_CAP);
    if (t == 0) cls_cnt[cls] = c;
    if (t < c) cls_rows[cls * CLS_CAP + t] = rs[t];
    int np = c * (c - 1) / 2;
    for (int base = 0; base < np * 8; base += 256) {
        int slot = base + t;
        if (slot < np * 8) {
            int p = slot >> 3, l = slot & 7;   // 8 aligned lanes per pair
            int a, b; pair_decode(p, a, b);
            const float4* pa = (const float4*)(emb + (size_t)rs[a] * D_SIZE) + l * 8;
            const float4* pb = (const float4*)(emb + (size_t)rs[b] * D_SIZE) + l * 8;
            float s = 0.0f;
#pragma unroll
            for (int k = 0; k < 8; ++k) {
                float4 x = pa[k], y = pb[k];
                s = fmaf(x.x, y.x, fmaf(x.y, y.y, fmaf(x.z, y.z, fmaf(x.w, y.w, s))));
            }
            s += __shfl_xor(s, 1, 64);
            s += __shfl_xor(s, 2, 64);
            s += __shfl_xor(s, 4, 64);
            if (l == 0) {
                if (p < PCAP) psims[cls * PCAP + p] = s;
                unsigned int e = enc_f32(s);
                atomicMin(&smin[a], e);
                atomicMin(&smin[b], e);
            }
        }
    }
    __syncthreads();
    if (t < c) pos_min[rs[t]] = dec_f32(smin[t]);
}

// ---- K2: the ONE GEMM (triangular tiles) — exact r9 body ----
// part[k*B + row]: m-side writes k=bj (bj>=bi), n-side k=bi (bi<bj);
// every line written by exactly one tile (no false sharing).
// C/D layout (16x16x32): col = lane&15, row = (lane>>4)*4 + reg  [m89/m91]
__global__ __launch_bounds__(256, 3) void neg_kernel(
    const unsigned short* __restrict__ embb, const int* __restrict__ labels,
    const float* __restrict__ pos_min,
    float* __restrict__ part_sum, float* __restrict__ part_max)
{
    // XCD-aware bijective swizzle (2080 % 8 == 0), then triangular decode
    int bt = (blockIdx.x & 7) * (NBLK >> 3) + (blockIdx.x >> 3);
    int bi = 0, rem = bt;
    while (rem >= (NT - bi)) { rem -= (NT - bi); ++bi; }
    const int bj = bi + rem;
    const int m0 = bi * TM, n0 = bj * TM;
    const bool isdiag = (bi == bj);

    const int tid = threadIdx.x;
    const int lane = tid & 63;
    const int w = tid >> 6;
    const int wm = w >> 1, wn = w & 1;

    __shared__ unsigned char As[2][TM * 64];
    __shared__ unsigned char Bs[2][TM * 64];

    const unsigned short* gA[2];
    const unsigned short* gB[2];
    int lofs[2];
#pragma unroll
    for (int s = 0; s < 2; ++s) {
        int r = w * 32 + s * 16 + (lane >> 2);
        int c = (lane & 3) ^ ((r >> 1) & 3);
        gA[s] = embb + (size_t)(m0 + r) * D_SIZE + c * 8;
        gB[s] = embb + (size_t)(n0 + r) * D_SIZE + c * 8;
        lofs[s] = (w * 32 + s * 16) * 64;
    }
#pragma unroll
    for (int s = 0; s < 2; ++s) { glds16(gA[s], As[0] + lofs[s]); glds16(gB[s], Bs[0] + lofs[s]); }

    const int col = lane & 15;
    const int quad = lane >> 4;
    const int xsw = (quad ^ ((col >> 1) & 3)) * 16;
    const int aoff0 = (wm * 64 + col) * 64 + xsw;
    const int boff0 = (wn * 64 + col) * 64 + xsw;

    f32x4 acc[4][4];
#pragma unroll
    for (int fi = 0; fi < 4; ++fi)
#pragma unroll
        for (int fj = 0; fj < 4; ++fj)
            acc[fi][fj] = (f32x4){0.0f, 0.0f, 0.0f, 0.0f};

#pragma unroll
    for (int it = 0; it < D_SIZE / TK; ++it) {
        const int st = it & 1;
        __syncthreads();   // stage st's staging complete
        if (it + 1 < D_SIZE / TK) {
            const int k1 = (it + 1) * TK;
#pragma unroll
            for (int s = 0; s < 2; ++s) {
                glds16(gA[s] + k1, As[st ^ 1] + lofs[s]);
                glds16(gB[s] + k1, Bs[st ^ 1] + lofs[s]);
            }
        }
        bf16x8 af[4], bf[4];
#pragma unroll
        for (int f = 0; f < 4; ++f) {
            af[f] = __builtin_bit_cast(bf16x8, *(const uint4*)(As[st] + aoff0 + f * 1024));
            bf[f] = __builtin_bit_cast(bf16x8, *(const uint4*)(Bs[st] + boff0 + f * 1024));
        }
#pragma unroll
        for (int fi = 0; fi < 4; ++fi)
#pragma unroll
            for (int fj = 0; fj < 4; ++fj)
                acc[fi][fj] = __builtin_amdgcn_mfma_f32_16x16x32_bf16(
                    af[fi], bf[fj], acc[fi][fj], 0, 0, 0);
    }

    // ---- branch-free sentinel epilogue, sched-fenced per fj-group ----
    const float K1 = 72.13475204444817f;   /* BETA*log2(e) */
    const float K2 = -36.067376022224085f; /* -BETA*BASE*log2(e) */
    int ljv[4]; float pmc[4], nsn[4], nmx[4];
#pragma unroll
    for (int fj = 0; fj < 4; ++fj) {
        int cl = wn * 64 + fj * 16 + col;
        ljv[fj] = labels[n0 + cl];
        pmc[fj] = pos_min[n0 + cl] - MARGIN;
        nsn[fj] = 0.0f;
        nmx[fj] = -3.0f;
    }

#pragma unroll
    for (int fi = 0; fi < 4; ++fi) {
        int gi0 = m0 + wm * 64 + fi * 16 + quad * 4;
        int lir[4]; float pmr[4], msn[4], mmx[4];
#pragma unroll
        for (int r = 0; r < 4; ++r) {
            lir[r] = labels[gi0 + r];
            pmr[r] = pos_min[gi0 + r] - MARGIN;
            msn[r] = 0.0f;
            mmx[r] = -3.0f;
        }
        __builtin_amdgcn_sched_barrier(0);
#pragma unroll
        for (int fj = 0; fj < 4; ++fj) {
#pragma unroll
            for (int r = 0; r < 4; ++r) {
                float s = acc[fi][fj][r];
                float sm = (lir[r] != ljv[fj]) ? s : -3.0f;
                float e = fexp2(fmaf(sm, K1, K2));
                mmx[r] = fmaxf(mmx[r], sm);
                nmx[fj] = fmaxf(nmx[fj], sm);
                msn[r] += (sm > pmr[r]) ? e : 0.0f;
                nsn[fj] += (sm > pmc[fj]) ? e : 0.0f;
            }
            __builtin_amdgcn_sched_barrier(0);
        }
        // 16-lane (col) reduction via DPP — VALU, no LDS pipe
#pragma unroll
        for (int r = 0; r < 4; ++r) red16(msn[r], mmx[r]);
        if (col == 0) {
            *(float4*)(&part_sum[(size_t)bj * B_SIZE + gi0]) =
                make_float4(msn[0], msn[1], msn[2], msn[3]);
            *(float4*)(&part_max[(size_t)bj * B_SIZE + gi0]) =
                make_float4(mmx[0], mmx[1], mmx[2], mmx[3]);
        }
        __builtin_amdgcn_sched_barrier(0);
    }
    if (!isdiag) {
#pragma unroll
        for (int m = 16; m < 64; m <<= 1) {
#pragma unroll
            for (int fj = 0; fj < 4; ++fj) {
                nsn[fj] += __shfl_xor(nsn[fj], m, 64);
                nmx[fj] = fmaxf(nmx[fj], __shfl_xor(nmx[fj], m, 64));
            }
        }
        if (quad == 0) {
#pragma unroll
            for (int fj = 0; fj < 4; ++fj) {
                int gj = n0 + wn * 64 + fj * 16 + col;
                part_sum[(size_t)bi * B_SIZE + gj] = nsn[fj];
                part_max[(size_t)bi * B_SIZE + gj] = nmx[fj];
            }
        }
    }
}

// ---- K2b: transpose partials [64][8192] -> [8192][64] (both arrays) ----
// Fully coalesced loads and stores; LDS 64x65 breaks bank conflicts.
__global__ __launch_bounds__(256) void transpose_kernel(
    const float* __restrict__ part_sum, const float* __restrict__ part_max,
    float* __restrict__ pts, float* __restrict__ ptm) {
    __shared__ float tile[64][65];
    const int r0 = blockIdx.x * 64;
    const int tx = threadIdx.x & 63;
    const int tg = threadIdx.x >> 6;   // 0..3
#pragma unroll
    for (int i = 0; i < 16; ++i) {
        int k = tg * 16 + i;
        tile[k][tx] = part_sum[(size_t)k * B_SIZE + r0 + tx];
    }
    __syncthreads();
#pragma unroll
    for (int i = 0; i < 16; ++i) {
        int row = tg * 16 + i;
        pts[(size_t)(r0 + row) * NT + tx] = tile[tx][row];
    }
    __syncthreads();
#pragma unroll
    for (int i = 0; i < 16; ++i) {
        int k = tg * 16 + i;
        tile[k][tx] = part_max[(size_t)k * B_SIZE + r0 + tx];
    }
    __syncthreads();
#pragma unroll
    for (int i = 0; i < 16; ++i) {
        int row = tg * 16 + i;
        ptm[(size_t)(r0 + row) * NT + tx] = tile[tx][row];
    }
}

// ---- K3: per-class reduce partials (coalesced float4 reads) + sum_pos ----
__global__ __launch_bounds__(256) void final_kernel(
    const float* __restrict__ emb, const int* __restrict__ cls_cnt,
    const int* __restrict__ cls_rows, const float* __restrict__ psims,
    const float* __restrict__ pts, const float* __restrict__ ptm,
    float* __restrict__ cls_term, float* __restrict__ cls_valid) {
    int cls = blockIdx.x;
    __shared__ int rs[CLS_CAP];
    __shared__ float snm[CLS_CAP];
    __shared__ float sneg[CLS_CAP];
    __shared__ float ssum[CLS_CAP];
    int t = threadIdx.x;
    int c = min(cls_cnt[cls], CLS_CAP);
    if (t < CLS_CAP) ssum[t] = 0.0f;
    if (t < c) rs[t] = cls_rows[cls * CLS_CAP + t];
    __syncthreads();
    // transposed partials: row's 64 k-slots contiguous -> 8 lanes/row,
    // each lane 2 float4 loads (sum) + 2 (max), fully coalesced.
    {
        int l = t & 7;
        for (int rr = t >> 3; rr < c; rr += 32) {
            int row = rs[rr];
            const float4* ps = (const float4*)(pts + (size_t)row * NT) + l * 2;
            const float4* pm = (const float4*)(ptm + (size_t)row * NT) + l * 2;
            float4 s0 = ps[0], s1 = ps[1];
            float4 m0 = pm[0], m1 = pm[1];
            float s = (s0.x + s0.y) + (s0.z + s0.w) + (s1.x + s1.y) + (s1.z + s1.w);
            float m = fmaxf(fmaxf(fmaxf(m0.x, m0.y), fmaxf(m0.z, m0.w)),
                            fmaxf(fmaxf(m1.x, m1.y), fmaxf(m1.z, m1.w)));
            s += __shfl_xor(s, 1, 64); m = fmaxf(m, __shfl_xor(m, 1, 64));
            s += __shfl_xor(s, 2, 64); m = fmaxf(m, __shfl_xor(m, 2, 64));
            s += __shfl_xor(s, 4, 64); m = fmaxf(m, __shfl_xor(m, 4, 64));
            if (l == 0) { sneg[rr] = s; snm[rr] = m; }
        }
    }
    __syncthreads();
    int np = c * (c - 1) / 2;
    if (np <= PCAP) {
        for (int p = t; p < np; p += 256) {
            float s = psims[cls * PCAP + p];
            int a, b; pair_decode(p, a, b);
            float e = __expf(-ALPHA * (s - BASE));
            if (s - MARGIN < snm[a]) atomicAdd(&ssum[a], e);
            if (s - MARGIN < snm[b]) atomicAdd(&ssum[b], e);
        }
    } else {
        // fallback: recompute dots, 8 lanes per pair
        for (int base = 0; base < np * 8; base += 256) {
            int slot = base + t;
            if (slot < np * 8) {
                int p = slot >> 3, l = slot & 7;
                int a, b; pair_decode(p, a, b);
                const float4* pa = (const float4*)(emb + (size_t)rs[a] * D_SIZE) + l * 8;
                const float4* pb = (const float4*)(emb + (size_t)rs[b] * D_SIZE) + l * 8;
                float s = 0.0f;
#pragma unroll
                for (int k = 0; k < 8; ++k) {
                    float4 x = pa[k], y = pb[k];
                    s = fmaf(x.x, y.x, fmaf(x.y, y.y, fmaf(x.z, y.z, fmaf(x.w, y.w, s))));
                }
                s += __shfl_xor(s, 1, 64);
                s += __shfl_xor(s, 2, 64);
                s += __shfl_xor(s, 4, 64);
                if (l == 0) {
                    float e = __expf(-ALPHA * (s - BASE));
                    if (s - MARGIN < snm[a]) atomicAdd(&ssum[a], e);
                    if (s - MARGIN < snm[b]) atomicAdd(&ssum[b], e);
                }
            }
        }
    }
    __syncthreads();
    // per-class term: rows live on threads 0..c-1 (all in wave 0) -> shfl reduce
    if (t < 64) {
        float term = 0.0f, valid = 0.0f;
        if (t < c) {
            float sp = ssum[t], sn = sneg[t];
            if (sp > 0.0f && sn > 0.0f) {
                term = log1pf(sp) * (1.0f / ALPHA) + log1pf(sn) * (1.0f / BETA);
                valid = 1.0f;
            }
        }
#pragma unroll
        for (int m = 1; m < 64; m <<= 1) {
            term += __shfl_xor(term, m, 64);
            valid += __shfl_xor(valid, m, 64);
        }
        if (t == 0) { cls_term[cls] = term; cls_valid[cls] = valid; }
    }
}

// ---- K4: fold 1024 class terms -> out ----
__global__ __launch_bounds__(256) void finalize_kernel(
    const float* __restrict__ cls_term, const float* __restrict__ cls_valid,
    float* __restrict__ out) {
    __shared__ float st[256];
    __shared__ float sc[256];
    int t = threadIdx.x;
    float tot = 0.0f, cnt = 0.0f;
#pragma unroll
    for (int i = 0; i < N_CLS / 256; ++i) {
        tot += cls_term[i * 256 + t];
        cnt += cls_valid[i * 256 + t];
    }
    st[t] = tot; sc[t] = cnt;
    __syncthreads();
    for (int s = 128; s > 0; s >>= 1) {
        if (t < s) { st[t] += st[t + s]; sc[t] += sc[t + s]; }
        __syncthreads();
    }
    if (t == 0) out[0] = st[0] / fmaxf(sc[0], 1.0f);
}

extern "C" void kernel_launch(void* const* d_in, const int* in_sizes, int n_in,
                              void* d_out, int out_size, void* d_ws, size_t ws_size,
                              hipStream_t stream) {
    const float* emb = (const float*)d_in[0];
    const int* labels = (const int*)d_in[1];
    float* out = (float*)d_out;

    // ws: embb 4MB | part_sum 2MB | part_max 2MB | pts 2MB | ptm 2MB |
    //     psims 1MB | cls_rows 256KB | pos_min 32KB | cls_term/valid/cnt
    unsigned short* embb = (unsigned short*)d_ws;
    float* part_sum = (float*)(embb + (size_t)B_SIZE * D_SIZE);
    float* part_max = part_sum + (size_t)NT * B_SIZE;
    float* pts = part_max + (size_t)NT * B_SIZE;
    float* ptm = pts + (size_t)B_SIZE * NT;
    float* psims = ptm + (size_t)B_SIZE * NT;
    int* cls_rows = (int*)(psims + (size_t)N_CLS * PCAP);
    float* pos_min = (float*)(cls_rows + N_CLS * CLS_CAP);
    float* cls_term = pos_min + B_SIZE;
    float* cls_valid = cls_term + N_CLS;
    int* cls_cnt = (int*)(cls_valid + N_CLS);

    conv_pos_kernel<<<dim3(N_CLS + NCONV), dim3(256), 0, stream>>>(
        emb, labels, embb, pos_min, psims, cls_cnt, cls_rows);
    neg_kernel<<<dim3(NBLK), dim3(256), 0, stream>>>(
        embb, labels, pos_min, part_sum, part_max);
    transpose_kernel<<<dim3(B_SIZE / 64), dim3(256), 0, stream>>>(
        part_sum, part_max, pts, ptm);
    final_kernel<<<dim3(N_CLS), dim3(256), 0, stream>>>(
        emb, cls_cnt, cls_rows, psims, pts, ptm, cls_term, cls_valid);
    finalize_kernel<<<dim3(1), dim3(256), 0, stream>>>(cls_term, cls_valid, out);
}